// Round 21
// baseline (587.335 us; speedup 1.0000x reference)
//
#include <hip/hip_runtime.h>

typedef unsigned short u16;
typedef unsigned int u32;
typedef short bf16x8 __attribute__((ext_vector_type(8)));
typedef float f32x4 __attribute__((ext_vector_type(4)));

#define Tlen 4096
#define NTOK 8192
#define NCH  256
#define CH   16

// ---- workspace layout (float offsets) ----
enum : int {
  OFF_EMB     = 16,
  OFF_INPUT   = OFF_EMB + 1536,
  OFF_INPROJW = OFF_INPUT + 32768,
  OFF_INPROJB = OFF_INPROJW + 1024,
  OFF_BLKINW  = OFF_INPROJB + 256,
  OFF_BLKINB  = OFF_BLKINW + 1048576,
  OFF_CONVW   = OFF_BLKINB + 4096,
  OFF_CONVB   = OFF_CONVW + 8192,
  OFF_XPROJW  = OFF_CONVB + 2048,
  OFF_DTW     = OFF_XPROJW + 98304,
  OFF_DTB     = OFF_DTW + 32768,
  OFF_A       = OFF_DTB + 2048,
  OFF_DP      = OFF_A + 32768,
  OFF_BLKOUTW = OFF_DP + 2048,
  OFF_BLKOUTB = OFF_BLKOUTW + 524288,
  OFF_LNG     = OFF_BLKOUTB + 1024,
  OFF_LNB     = OFF_LNG + 1024,
  OFF_HEADW   = OFF_LNB + 1024,
  OFF_HEADB   = OFF_HEADW + 1536,
  OFF_OUTPW   = OFF_HEADB + 16,
  OFF_OUTPB   = OFF_OUTPW + 1024,
  OFF_X       = OFF_OUTPB + 16,           // f32 (NTOK,256) residual
  OFF_DT      = OFF_X + NTOK*256,         // bf16 (NTOK,512) dt
  OFF_SD      = OFF_DT + NTOK*256,        // f32 (2*NCH=512,512) chunk dt-sums
  OFF_BM      = OFF_SD + 262144,          // f32 (NTOK,16)
  OFF_CM      = OFF_BM + 131072,          // f32 (NTOK,16)
  OFF_XSBL    = OFF_CM + 131072,          // overlay: bf16 xs(NTOK,512); then bf16 BLHS(512,512,16)
  OFF_Z16     = OFF_XSBL + NTOK*256,      // bf16 z (NTOK,512)
  OFF_XC16    = OFF_Z16 + NTOK*256,       // bf16 xc (NTOK,512); scan3 overwrites with y
  OFF_X16     = OFF_XC16 + NTOK*256,      // bf16 x (NTOK,256) residual copy (GEMM A)
  OFF_WIN16   = OFF_X16 + NTOK*128,       // bf16 blk_in_w (4,1024,256)
  OFF_WOUT16  = OFF_WIN16 + 524288,       // bf16 blk_out_w (4,256,512)
  OFF_BXD16   = OFF_WOUT16 + 262144,      // bf16 (4,48,512)
  OFF_T16     = OFF_BXD16 + 49152,        // bf16 (NTOK,32) T zero-padded
  OFF_DTW16   = OFF_T16 + NTOK*16,        // bf16 (4,512,32) dtw zero-padded
  OFF_TOT     = OFF_DTW16 + 32768,
};

__device__ inline float bf2f(u16 u) { return __uint_as_float(((u32)u) << 16); }
__device__ inline u16 f2bf(float f) {
  u32 x = __float_as_uint(f);
  u32 r = x + 0x7fffu + ((x >> 16) & 1u);
  return (u16)(r >> 16);
}
__device__ inline u32 pk2(float a, float b) {
  return (u32)f2bf(a) | ((u32)f2bf(b) << 16);
}

// ---- ws_size shortfall sentinel ----
__global__ void k_sentinel(u32* dout, int nw) {
  int i = blockIdx.x * blockDim.x + threadIdx.x;
  if (i < nw) dout[i] = 0x46404640u;
}

// ---- dtype detection ----
__global__ void k_detect(const u16* emb, int n, int* flag) {
  __shared__ int bad;
  if (threadIdx.x == 0) bad = 0;
  __syncthreads();
  int local = 0;
  for (int i = threadIdx.x; i < n; i += blockDim.x) {
    float v = bf2f(emb[i]);
    if (!(fabsf(v) < 100.0f)) local = 1;
  }
  if (local) atomicOr(&bad, 1);
  __syncthreads();
  if (threadIdx.x == 0) flag[0] = bad ? 0 : 1;
}

// ---- convert all float tensors to f32 in ws (op=1: v -> -exp(v)) ----
struct Seg { const void* src; int n; int off; int op; };
struct ConvArgs { Seg seg[21]; int nseg; };

__global__ void k_convert(ConvArgs a, float* ws, const int* flag) {
  int isb = *flag;
  for (int sgi = 0; sgi < a.nseg; sgi++) {
    Seg sg = a.seg[sgi];
    for (int i = blockIdx.x * blockDim.x + threadIdx.x; i < sg.n;
         i += gridDim.x * blockDim.x) {
      float v;
      if (isb) v = bf2f(((const u16*)sg.src)[i]);
      else     v = ((const float*)sg.src)[i];
      if (sg.op) v = -__expf(v);
      ws[sg.off + i] = v;
    }
  }
}

// ---- bf16 copies of GEMM weights (+ dtw16 zero-padded K=32) ----
__global__ void k_w16(float* ws) {
  u16* win = (u16*)(ws + OFF_WIN16);
  u16* wout = (u16*)(ws + OFF_WOUT16);
  u16* dtw16 = (u16*)(ws + OFF_DTW16);
  const int N1 = 1048576, N2 = N1 + 524288, N3 = N2 + 4 * 512 * 32;
  for (int i = blockIdx.x * blockDim.x + threadIdx.x; i < N3;
       i += gridDim.x * blockDim.x) {
    if (i < N1) {
      win[i] = f2bf(ws[OFF_BLKINW + i]);
    } else if (i < N2) {
      wout[i - N1] = f2bf(ws[OFF_BLKOUTW + i - N1]);
    } else {
      int j = i - N2;
      int l = j / (512 * 32), rem = j - l * (512 * 32);
      int row = rem >> 5, k = rem & 31;
      dtw16[j] = (k < 16) ? f2bf(ws[OFF_DTW + l * 8192 + row * 16 + k]) : 0;
    }
  }
}

// ---- build BXD panel: rows 0..31 = xpw[16:48] (B,C); rows 32..47 = xpw[0:16] ----
__global__ void k_bxd(float* ws) {
  u16* bxd = (u16*)(ws + OFF_BXD16);
  const int NXD = 4 * 48 * 512;
  for (int idx = blockIdx.x * blockDim.x + threadIdx.x; idx < NXD;
       idx += gridDim.x * blockDim.x) {
    int l = idx / (48 * 512);
    int rem = idx - l * (48 * 512);
    int row = rem >> 9, k = rem & 511;
    const float* xpw = ws + OFF_XPROJW + l * 24576;
    float v = (row < 32) ? xpw[(16 + row) * 512 + k] : xpw[(row - 32) * 512 + k];
    bxd[idx] = f2bf(v);
  }
}

// ---- x = emb[seq] + input @ inproj_w.T + inproj_b ----
__global__ __launch_bounds__(256) void k_embed(const int* seq, float* ws) {
  int n = blockIdx.x, d = threadIdx.x;
  int s = seq[n];
  float4 iv = *(const float4*)(ws + OFF_INPUT + n * 4);
  float4 wv = *(const float4*)(ws + OFF_INPROJW + d * 4);
  float acc = ws[OFF_EMB + s * 256 + d] + ws[OFF_INPROJB + d]
            + iv.x * wv.x + iv.y * wv.y + iv.z * wv.z + iv.w * wv.w;
  ws[OFF_X + (size_t)n * 256 + d] = acc;
  ((u16*)(ws + OFF_X16))[(size_t)n * 256 + d] = f2bf(acc);
}

// ---- MFMA in-proj: LDS-staged 128x128 tile, K=256 (R13-proven) ----
__global__ __launch_bounds__(256) void k_gemm_in(float* ws, int l) {
  __shared__ u16 As[128][40];
  __shared__ u16 Bs[128][40];
  __shared__ u16 ot[64][136];
  int m0 = blockIdx.x * 128, n0g = blockIdx.y * 128;
  int t = threadIdx.x;
  int w = t >> 6, lane = t & 63;
  int fr = lane & 15, fq = lane >> 4;
  int wr = (w >> 1) * 64, wc = (w & 1) * 64;
  const u16* Ab = (const u16*)(ws + OFF_X16);
  const u16* Bb = (const u16*)(ws + OFF_WIN16) + (size_t)l * 1024 * 256;
  const float* bias = ws + OFF_BLKINB + l * 1024;
  f32x4 acc[4][4] = {};
  for (int k0 = 0; k0 < 256; k0 += 32) {
    __syncthreads();
    #pragma unroll
    for (int cc = 0; cc < 2; cc++) {
      int c = t + cc * 256;
      int row = c >> 2, cg = (c & 3) * 8;
      *(uint4*)&As[row][cg] =
          *(const uint4*)(Ab + (size_t)(m0 + row) * 256 + k0 + cg);
      *(uint4*)&Bs[row][cg] =
          *(const uint4*)(Bb + (size_t)(n0g + row) * 256 + k0 + cg);
    }
    __syncthreads();
    bf16x8 af[4], bf_[4];
    #pragma unroll
    for (int f = 0; f < 4; f++) {
      af[f]  = *(const bf16x8*)&As[wr + f * 16 + fr][fq * 8];
      bf_[f] = *(const bf16x8*)&Bs[wc + f * 16 + fr][fq * 8];
    }
    #pragma unroll
    for (int i = 0; i < 4; i++)
      #pragma unroll
      for (int j = 0; j < 4; j++)
        acc[i][j] = __builtin_amdgcn_mfma_f32_16x16x32_bf16(af[i], bf_[j],
                                                            acc[i][j], 0, 0, 0);
  }
  u16* plane; int cb0;
  if (n0g < 512) { plane = (u16*)(ws + OFF_XSBL); cb0 = n0g; }
  else           { plane = (u16*)(ws + OFF_Z16);  cb0 = n0g - 512; }
  #pragma unroll
  for (int hh = 0; hh < 2; hh++) {
    __syncthreads();
    if ((w >> 1) == hh) {
      #pragma unroll
      for (int i = 0; i < 4; i++)
        #pragma unroll
        for (int j = 0; j < 4; j++) {
          int col = wc + j * 16 + fr;
          float bv = bias[n0g + col];
          #pragma unroll
          for (int r = 0; r < 4; r++)
            ot[i * 16 + fq * 4 + r][col] = f2bf(acc[i][j][r] + bv);
        }
    }
    __syncthreads();
    int row = t >> 2, c0 = (t & 3) * 32;
    uint4 q0 = *(const uint4*)&ot[row][c0];
    uint4 q1 = *(const uint4*)&ot[row][c0 + 8];
    uint4 q2 = *(const uint4*)&ot[row][c0 + 16];
    uint4 q3 = *(const uint4*)&ot[row][c0 + 24];
    u16* dst = plane + (size_t)(m0 + hh * 64 + row) * 512 + cb0 + c0;
    *(uint4*)(dst + 0) = q0;
    *(uint4*)(dst + 8) = q1;
    *(uint4*)(dst + 16) = q2;
    *(uint4*)(dst + 24) = q3;
  }
}

// ---- causal depthwise conv + silu -> xc16 (rolling register window) ----
__global__ __launch_bounds__(512) void k_conv(float* ws, int l) {
  int n0 = blockIdx.x * 16;
  int d = threadIdx.x;
  const float* cw = ws + OFF_CONVW + l * 2048;
  float4 w4 = *(const float4*)(cw + d * 4);
  float cbv = ws[OFF_CONVB + l * 512 + d];
  const u16* xs16 = (const u16*)(ws + OFF_XSBL);
  u16* xc16 = (u16*)(ws + OFF_XC16);
  float xm3, xm2, xm1;
  if ((n0 & (Tlen - 1)) == 0) {
    xm3 = xm2 = xm1 = 0.f;
  } else {
    xm3 = bf2f(xs16[(size_t)(n0 - 3) * 512 + d]);
    xm2 = bf2f(xs16[(size_t)(n0 - 2) * 512 + d]);
    xm1 = bf2f(xs16[(size_t)(n0 - 1) * 512 + d]);
  }
  #pragma unroll
  for (int tok = 0; tok < 16; tok++) {
    int n = n0 + tok;
    float xc = bf2f(xs16[(size_t)n * 512 + d]);
    float acc = cbv + xm3 * w4.x + xm2 * w4.y + xm1 * w4.z + xc * w4.w;
    float sv = acc / (1.f + __expf(-acc));   // silu
    xc16[(size_t)n * 512 + d] = f2bf(sv);
    xm3 = xm2; xm2 = xm1; xm1 = xc;
  }
}

// ---- MFMA B/C/T proj: direct pipelined, 3 B-frags (BM, CM, T->bf16 padded) ----
__global__ __launch_bounds__(256) void k_gemm_bct(float* ws, int l) {
  int m0 = blockIdx.x * 64;
  int w = threadIdx.x >> 6, lane = threadIdx.x & 63;
  const u16* Ab = (const u16*)(ws + OFF_XC16);
  const u16* Bb = (const u16*)(ws + OFF_BXD16) + (size_t)l * 48 * 512;
  int ak = (lane >> 4) * 8;
  const u16* ap = Ab + (size_t)(m0 + w * 16 + (lane & 15)) * 512 + ak;
  int rowbase = w * 16 + (lane >> 4) * 4;
  const u16* bp = Bb + (size_t)(lane & 15) * 512 + ak;
  f32x4 acc[3] = {};
  bf16x8 a0 = *(const bf16x8*)ap;
  bf16x8 b0[3];
  #pragma unroll
  for (int j = 0; j < 3; j++) b0[j] = *(const bf16x8*)(bp + (size_t)j * 8192);
  #pragma unroll 2
  for (int k0 = 1; k0 < 16; k0++) {
    bf16x8 a1 = *(const bf16x8*)(ap + k0 * 32);
    bf16x8 b1[3];
    #pragma unroll
    for (int j = 0; j < 3; j++)
      b1[j] = *(const bf16x8*)(bp + (size_t)j * 8192 + k0 * 32);
    #pragma unroll
    for (int j = 0; j < 3; j++)
      acc[j] = __builtin_amdgcn_mfma_f32_16x16x32_bf16(a0, b0[j], acc[j], 0, 0, 0);
    a0 = a1;
    #pragma unroll
    for (int j = 0; j < 3; j++) b0[j] = b1[j];
  }
  #pragma unroll
  for (int j = 0; j < 3; j++)
    acc[j] = __builtin_amdgcn_mfma_f32_16x16x32_bf16(a0, b0[j], acc[j], 0, 0, 0);
  int c = lane & 15;
  u16* t16 = (u16*)(ws + OFF_T16);
  #pragma unroll
  for (int r = 0; r < 4; r++) {
    ws[OFF_BM + (size_t)(m0 + rowbase + r) * 16 + c] = acc[0][r];
    ws[OFF_CM + (size_t)(m0 + rowbase + r) * 16 + c] = acc[1][r];
    t16[(size_t)(m0 + rowbase + r) * 32 + c] = f2bf(acc[2][r]);
    t16[(size_t)(m0 + rowbase + r) * 32 + 16 + c] = 0;
  }
}

// ---- MFMA dt: dt = softplus(T16 @ dtw16^T + b), K=32 single step ----
__global__ __launch_bounds__(256) void k_dt16(float* ws, int l) {
  __shared__ u16 dts[64][136];
  int m0 = blockIdx.x * 64;
  int c0g = blockIdx.y * 64;
  int t = threadIdx.x;
  int w = t >> 6, lane = t & 63;
  int fr = lane & 15, fq = lane >> 4;
  const u16* Ab = (const u16*)(ws + OFF_T16);
  const u16* Bb = (const u16*)(ws + OFF_DTW16) + (size_t)l * 512 * 32;
  bf16x8 a = *(const bf16x8*)(Ab + (size_t)(m0 + w * 16 + fr) * 32 + fq * 8);
  f32x4 acc[4] = {};
  #pragma unroll
  for (int j = 0; j < 4; j++) {
    bf16x8 b = *(const bf16x8*)(Bb + (size_t)(c0g + j * 16 + fr) * 32 + fq * 8);
    acc[j] = __builtin_amdgcn_mfma_f32_16x16x32_bf16(a, b, acc[j], 0, 0, 0);
  }
  const float* dtb = ws + OFF_DTB + l * 512;
  int rowbase = w * 16 + fq * 4;
  #pragma unroll
  for (int j = 0; j < 4; j++) {
    float bv = dtb[c0g + j * 16 + fr];
    #pragma unroll
    for (int r = 0; r < 4; r++) {
      float s = acc[j][r] + bv;
      float dtv = (s > 20.f) ? s : log1pf(__expf(s));
      dts[rowbase + r][j * 16 + fr] = f2bf(dtv);
    }
  }
  __syncthreads();
  u16* dt16 = (u16*)(ws + OFF_DT);
  int row = t >> 2, part = t & 3;
  uint4 v0 = *(const uint4*)&dts[row][part * 16];
  uint4 v1 = *(const uint4*)&dts[row][part * 16 + 8];
  u16* dst = dt16 + (size_t)(m0 + row) * 512 + c0g + part * 16;
  *(uint4*)dst = v0;
  *(uint4*)(dst + 8) = v1;
}

// ---- scan phase 1: CH=16 chunks (2 blocks/CU); BL stored bf16 ----
__global__ __launch_bounds__(512) void k_scan1(float* ws, int l) {
  __shared__ u16 dt_s[8][512];
  __shared__ u16 xc_s[8][512];
  __shared__ float Bls[CH * 16];
  int blk = blockIdx.x;
  int b = blk >> 8, ch = blk & 255;
  int d = threadIdx.x;
  int nbase = b * Tlen + ch * CH;
  if (d < CH * 16) Bls[d] = ws[OFF_BM + (size_t)nbase * 16 + d];
  const float* Ap = ws + OFF_A + l * 8192 + d * 16;
  float Ar[16];
  *(float4*)&Ar[0]  = *(const float4*)(Ap + 0);
  *(float4*)&Ar[4]  = *(const float4*)(Ap + 4);
  *(float4*)&Ar[8]  = *(const float4*)(Ap + 8);
  *(float4*)&Ar[12] = *(const float4*)(Ap + 12);
  float h[16];
  #pragma unroll
  for (int s = 0; s < 16; s++) h[s] = 0.f;
  float sumdt = 0.f;
  const u16* dtg = (const u16*)(ws + OFF_DT) + (size_t)nbase * 512;
  const u16* xcg = (const u16*)(ws + OFF_XC16) + (size_t)nbase * 512;
  int lr = d >> 6, lc = (d & 63) * 8;
  uint4 pd = *(const uint4*)(dtg + (size_t)lr * 512 + lc);
  uint4 px = *(const uint4*)(xcg + (size_t)lr * 512 + lc);
  for (int st = 0; st < 2; st++) {
    *(uint4*)&dt_s[lr][lc] = pd;
    *(uint4*)&xc_s[lr][lc] = px;
    if (st < 1) {
      pd = *(const uint4*)(dtg + (size_t)(8 + lr) * 512 + lc);
      px = *(const uint4*)(xcg + (size_t)(8 + lr) * 512 + lc);
    }
    __syncthreads();
    #pragma unroll
    for (int tk = 0; tk < 8; tk++) {
      int tt = st * 8 + tk;
      float dtv = bf2f(dt_s[tk][d]);
      float xv = bf2f(xc_s[tk][d]);
      sumdt += dtv;
      float dtx = dtv * xv;
      #pragma unroll
      for (int s = 0; s < 16; s++)
        h[s] = __expf(dtv * Ar[s]) * h[s] + dtx * Bls[tt * 16 + s];
    }
    __syncthreads();
  }
  ws[OFF_SD + (size_t)blk * 512 + d] = sumdt;
  u16* bl = (u16*)(ws + OFF_XSBL) + ((size_t)blk * 512 + d) * 16;
  u32 pk[8];
  #pragma unroll
  for (int i = 0; i < 8; i++) pk[i] = pk2(h[2 * i], h[2 * i + 1]);
  *(uint4*)(bl + 0) = *(uint4*)&pk[0];
  *(uint4*)(bl + 8) = *(uint4*)&pk[4];
}

// ---- scan phase 2: prefix over 256 chunks (bf16 BLHS in place) ----
__global__ __launch_bounds__(256) void k_scan2(float* ws, int l) {
  int q = blockIdx.x * 256 + threadIdx.x;   // 2*512*16 total
  int b = q >> 13, ds = q & 8191, d = ds >> 4;
  float Av = ws[OFF_A + l * 8192 + ds];
  u16* blhs = (u16*)(ws + OFF_XSBL);
  const float* sdp = ws + OFF_SD;
  size_t base = (size_t)(b * NCH) * 8192 + ds;
  size_t sbase = (size_t)(b * NCH) * 512 + d;
  float blv[4], sd[4];
  #pragma unroll
  for (int k = 0; k < 4; k++) {
    blv[k] = bf2f(blhs[base + (size_t)k * 8192]);
    sd[k] = sdp[sbase + (size_t)k * 512];
  }
  float h = 0.f;
  for (int g = 0; g < NCH / 4; g++) {
    float nblv[4], nsd[4];
    if (g < NCH / 4 - 1) {
      #pragma unroll
      for (int k = 0; k < 4; k++) {
        nblv[k] = bf2f(blhs[base + (size_t)(g * 4 + 4 + k) * 8192]);
        nsd[k] = sdp[sbase + (size_t)(g * 4 + 4 + k) * 512];
      }
    }
    #pragma unroll
    for (int k = 0; k < 4; k++) {
      blhs[base + (size_t)(g * 4 + k) * 8192] = f2bf(h);   // h at chunk start
      h = __expf(sd[k] * Av) * h + blv[k];
    }
    #pragma unroll
    for (int k = 0; k < 4; k++) { blv[k] = nblv[k]; sd[k] = nsd[k]; }
  }
}

// ---- scan phase 3: CH=16 chunks; HS bf16; y -> bf16 over xc plane ----
__global__ __launch_bounds__(512) void k_scan3(float* ws, int l) {
  __shared__ u16 dt_s[8][512];
  __shared__ u16 xc_s[8][512];
  __shared__ u16 z_s[8][512];
  __shared__ u16 y_s[8][512];
  __shared__ float Bls[CH * 16];
  __shared__ float Cls[CH * 16];
  int blk = blockIdx.x;
  int b = blk >> 8, ch = blk & 255;
  int d = threadIdx.x;
  int nbase = b * Tlen + ch * CH;
  if (d < CH * 16) {
    Bls[d] = ws[OFF_BM + (size_t)nbase * 16 + d];
    Cls[d] = ws[OFF_CM + (size_t)nbase * 16 + d];
  }
  const float* Ap = ws + OFF_A + l * 8192 + d * 16;
  float Ar[16];
  *(float4*)&Ar[0]  = *(const float4*)(Ap + 0);
  *(float4*)&Ar[4]  = *(const float4*)(Ap + 4);
  *(float4*)&Ar[8]  = *(const float4*)(Ap + 8);
  *(float4*)&Ar[12] = *(const float4*)(Ap + 12);
  float Dv = ws[OFF_DP + l * 512 + d];
  const u16* hsp = (const u16*)(ws + OFF_XSBL) + ((size_t)blk * 512 + d) * 16;
  uint4 hq0 = *(const uint4*)(hsp + 0);
  uint4 hq1 = *(const uint4*)(hsp + 8);
  float h[16];
  {
    const u32* hw = (const u32*)&hq0;
    #pragma unroll
    for (int i = 0; i < 4; i++) {
      h[2 * i] = bf2f((u16)hw[i]);
      h[2 * i + 1] = bf2f((u16)(hw[i] >> 16));
    }
    const u32* hw1 = (const u32*)&hq1;
    #pragma unroll
    for (int i = 0; i < 4; i++) {
      h[8 + 2 * i] = bf2f((u16)hw1[i]);
      h[8 + 2 * i + 1] = bf2f((u16)(hw1[i] >> 16));
    }
  }
  const u16* dtg = (const u16*)(ws + OFF_DT) + (size_t)nbase * 512;
  u16* xcg = (u16*)(ws + OFF_XC16) + (size_t)nbase * 512;  // xc in, y out
  const u16* zg = (const u16*)(ws + OFF_Z16) + (size_t)nbase * 512;
  int lr = d >> 6, lc = (d & 63) * 8;
  size_t off0 = (size_t)lr * 512 + lc;
  uint4 pd = *(const uint4*)(dtg + off0);
  uint4 px = *(const uint4*)(xcg + off0);
  uint4 pz = *(const uint4*)(zg + off0);
  for (int st = 0; st < 2; st++) {
    size_t goff = (size_t)(st * 8 + lr) * 512 + lc;
    *(uint4*)&dt_s[lr][lc] = pd;
    *(uint4*)&xc_s[lr][lc] = px;
    *(uint4*)&z_s[lr][lc]  = pz;
    if (st < 1) {
      size_t noff = (size_t)(8 + lr) * 512 + lc;
      pd = *(const uint4*)(dtg + noff);
      px = *(const uint4*)(xcg + noff);
      pz = *(const uint4*)(zg + noff);
    }
    __syncthreads();
    #pragma unroll
    for (int tk = 0; tk < 8; tk++) {
      int tt = st * 8 + tk;
      float dtv = bf2f(dt_s[tk][d]);
      float xv = bf2f(xc_s[tk][d]);
      float dtx = dtv * xv;
      float yacc = 0.f;
      #pragma unroll
      for (int s = 0; s < 16; s++) {
        h[s] = __expf(dtv * Ar[s]) * h[s] + dtx * Bls[tt * 16 + s];
        yacc += h[s] * Cls[tt * 16 + s];
      }
      float yv = yacc + Dv * xv;
      float zv = bf2f(z_s[tk][d]);
      float sz = zv / (1.f + __expf(-zv));
      y_s[tk][d] = f2bf(yv * sz);
    }
    __syncthreads();
    *(uint4*)(xcg + goff) = *(const uint4*)&y_s[lr][lc];
  }
}

// ---- MFMA out-proj: pipelined k-loop + residual + layernorm fused ----
__global__ __launch_bounds__(256) void k_gemm_out(float* ws, int l) {
  __shared__ float mxs[16][260];
  int m0 = blockIdx.x * 16;
  int w = threadIdx.x >> 6, lane = threadIdx.x & 63;
  const u16* Ab = (const u16*)(ws + OFF_XC16);   // y bf16
  const u16* Bb = (const u16*)(ws + OFF_WOUT16) + (size_t)l * 256 * 512;
  int ak = (lane >> 4) * 8;
  const u16* ap = Ab + (size_t)(m0 + (lane & 15)) * 512 + ak;
  const u16* bp = Bb + (size_t)(w * 64 + (lane & 15)) * 512 + ak;
  f32x4 acc[4] = {};
  bf16x8 a0 = *(const bf16x8*)ap;
  bf16x8 b0[4];
  #pragma unroll
  for (int j = 0; j < 4; j++) b0[j] = *(const bf16x8*)(bp + (size_t)j * 8192);
  #pragma unroll 2
  for (int k0 = 1; k0 < 16; k0++) {
    bf16x8 a1 = *(const bf16x8*)(ap + k0 * 32);
    bf16x8 b1[4];
    #pragma unroll
    for (int j = 0; j < 4; j++)
      b1[j] = *(const bf16x8*)(bp + (size_t)j * 8192 + k0 * 32);
    #pragma unroll
    for (int j = 0; j < 4; j++)
      acc[j] = __builtin_amdgcn_mfma_f32_16x16x32_bf16(a0, b0[j], acc[j], 0, 0, 0);
    a0 = a1;
    #pragma unroll
    for (int j = 0; j < 4; j++) b0[j] = b1[j];
  }
  #pragma unroll
  for (int j = 0; j < 4; j++)
    acc[j] = __builtin_amdgcn_mfma_f32_16x16x32_bf16(a0, b0[j], acc[j], 0, 0, 0);
  const float* ob = ws + OFF_BLKOUTB + l * 256;
  int rl = (lane >> 4) * 4;
  #pragma unroll
  for (int j = 0; j < 4; j++) {
    int c = w * 64 + j * 16 + (lane & 15);
    float bv = ob[c];
    #pragma unroll
    for (int r = 0; r < 4; r++)
      mxs[rl + r][c] = acc[j][r] + bv;
  }
  __syncthreads();
  int t = threadIdx.x;
  int g = t >> 4, ln = t & 15;
  int n = m0 + g;
  float* x = ws + OFF_X;
  const float* gamma = ws + OFF_LNG + l * 256;
  const float* beta = ws + OFF_LNB + l * 256;
  float v[16], s1 = 0.f, s2 = 0.f;
  #pragma unroll
  for (int i = 0; i < 16; i++) {
    int c = ln + i * 16;
    float xv = x[(size_t)n * 256 + c] + mxs[g][c];
    v[i] = xv; s1 += xv; s2 += xv * xv;
  }
  #pragma unroll
  for (int m = 8; m >= 1; m >>= 1) {
    s1 += __shfl_xor(s1, m, 64);
    s2 += __shfl_xor(s2, m, 64);
  }
  float mu = s1 * (1.f / 256.f);
  float var = s2 * (1.f / 256.f) - mu * mu;
  float rs = rsqrtf(var + 1e-5f);
  #pragma unroll
  for (int i = 0; i < 16; i++) {
    int c = ln + i * 16;
    mxs[g][c] = (v[i] - mu) * rs * gamma[c] + beta[c];
  }
  __syncthreads();
  int row = t >> 4, cb = (t & 15) * 16;
  float4 f0 = *(const float4*)&mxs[row][cb + 0];
  float4 f1 = *(const float4*)&mxs[row][cb + 4];
  float4 f2 = *(const float4*)&mxs[row][cb + 8];
  float4 f3 = *(const float4*)&mxs[row][cb + 12];
  float* xd = x + (size_t)(m0 + row) * 256 + cb;
  *(float4*)(xd + 0) = f0;
  *(float4*)(xd + 4) = f1;
  *(float4*)(xd + 8) = f2;
  *(float4*)(xd + 12) = f3;
  u32 p[8];
  p[0] = pk2(f0.x, f0.y);
  p[1] = pk2(f0.z, f0.w);
  p[2] = pk2(f1.x, f1.y);
  p[3] = pk2(f1.z, f1.w);
  p[4] = pk2(f2.x, f2.y);
  p[5] = pk2(f2.z, f2.w);
  p[6] = pk2(f3.x, f3.y);
  p[7] = pk2(f3.z, f3.w);
  u16* xd16 = (u16*)(ws + OFF_X16) + (size_t)(m0 + row) * 256 + cb;
  *(uint4*)(xd16 + 0) = *(uint4*)&p[0];
  *(uint4*)(xd16 + 8) = *(uint4*)&p[4];
}

// ---- heads ----
__global__ __launch_bounds__(256) void k_head(const float* ws, void* dout,
                                              const int* flag) {
  int t = threadIdx.x;
  int lane = t & 63, w = t >> 6;
  int n = blockIdx.x * 4 + w;
  const float* xr = ws + OFF_X + (size_t)n * 256;
  float xv[4];
  #pragma unroll
  for (int i = 0; i < 4; i++) xv[i] = xr[lane + 64 * i];
  float res[10];
  #pragma unroll
  for (int o = 0; o < 10; o++) {
    const float* wr = (o < 6) ? ws + OFF_HEADW + o * 256
                              : ws + OFF_OUTPW + (o - 6) * 256;
    float p = 0.f;
    #pragma unroll
    for (int i = 0; i < 4; i++) p += xv[i] * wr[lane + 64 * i];
    #pragma unroll
    for (int m = 32; m >= 1; m >>= 1) p += __shfl_xor(p, m, 64);
    res[o] = p;
  }
  int isb = flag[0];
  if (lane < 6) {
    float vv = res[lane] + ws[OFF_HEADB + lane];
    size_t idx = (size_t)n * 6 + lane;
    if (isb) ((u16*)dout)[idx] = f2bf(vv);
    else     ((float*)dout)[idx] = vv;
  } else if (lane < 10) {
    int o = lane - 6;
    float vv = res[lane] + ws[OFF_OUTPB + o];
    size_t idx = (size_t)NTOK * 6 + (size_t)n * 4 + o;
    if (isb) ((u16*)dout)[idx] = f2bf(vv);
    else     ((float*)dout)[idx] = vv;
  }
}

extern "C" void kernel_launch(void* const* d_in, const int* in_sizes, int n_in,
                              void* d_out, int out_size, void* d_ws, size_t ws_size,
                              hipStream_t stream) {
  (void)n_in;
  float* ws = (float*)d_ws;
  int* flag = (int*)d_ws;

  if (ws_size < (size_t)OFF_TOT * 4) {
    int nw = out_size / 2;
    k_sentinel<<<(nw + 255) / 256, 256, 0, stream>>>((u32*)d_out, nw);
    return;
  }

  k_detect<<<1, 256, 0, stream>>>((const u16*)d_in[2], in_sizes[2], flag);

  ConvArgs ca;
  int i = 0;
  auto add = [&](int idx, int n, int off, int op) {
    ca.seg[i].src = d_in[idx]; ca.seg[i].n = n;
    ca.seg[i].off = off; ca.seg[i].op = op; i++;
  };
  add(2, 1536, OFF_EMB, 0);      add(1, 32768, OFF_INPUT, 0);
  add(3, 1024, OFF_INPROJW, 0);  add(4, 256, OFF_INPROJB, 0);
  add(5, 1048576, OFF_BLKINW, 0); add(6, 4096, OFF_BLKINB, 0);
  add(7, 8192, OFF_CONVW, 0);    add(8, 2048, OFF_CONVB, 0);
  add(9, 98304, OFF_XPROJW, 0);  add(10, 32768, OFF_DTW, 0);
  add(11, 2048, OFF_DTB, 0);     add(12, 32768, OFF_A, 1);  // A = -exp(A_log)
  add(13, 2048, OFF_DP, 0);      add(14, 524288, OFF_BLKOUTW, 0);
  add(15, 1024, OFF_BLKOUTB, 0); add(16, 1024, OFF_LNG, 0);
  add(17, 1024, OFF_LNB, 0);     add(18, 1536, OFF_HEADW, 0);
  add(19, 6, OFF_HEADB, 0);      add(20, 1024, OFF_OUTPW, 0);
  add(21, 4, OFF_OUTPB, 0);
  ca.nseg = i;
  k_convert<<<512, 256, 0, stream>>>(ca, ws, flag);
  k_w16<<<512, 256, 0, stream>>>(ws);
  k_bxd<<<384, 256, 0, stream>>>(ws);

  k_embed<<<NTOK, 256, 0, stream>>>((const int*)d_in[0], ws);

  for (int l = 0; l < 4; l++) {
    k_gemm_in<<<dim3(64, 8), 256, 0, stream>>>(ws, l);
    k_conv<<<NTOK / 16, 512, 0, stream>>>(ws, l);
    k_gemm_bct<<<128, 256, 0, stream>>>(ws, l);
    k_dt16<<<dim3(128, 8), 256, 0, stream>>>(ws, l);
    k_scan1<<<2 * NCH, 512, 0, stream>>>(ws, l);
    k_scan2<<<64, 256, 0, stream>>>(ws, l);
    k_scan3<<<2 * NCH, 512, 0, stream>>>(ws, l);
    k_gemm_out<<<NTOK / 16, 256, 0, stream>>>(ws, l);
  }

  k_head<<<NTOK / 4, 256, 0, stream>>>(ws, d_out, flag);
}

// Round 22
// 549.934 us; speedup vs baseline: 1.0680x; 1.0680x over previous
//
#include <hip/hip_runtime.h>

typedef unsigned short u16;
typedef unsigned int u32;
typedef short bf16x8 __attribute__((ext_vector_type(8)));
typedef float f32x4 __attribute__((ext_vector_type(4)));

#define Tlen 4096
#define NTOK 8192
#define NCH  128
#define CH   32

// ---- workspace layout (float offsets) ----
enum : int {
  OFF_EMB     = 16,
  OFF_INPUT   = OFF_EMB + 1536,
  OFF_INPROJW = OFF_INPUT + 32768,
  OFF_INPROJB = OFF_INPROJW + 1024,
  OFF_BLKINW  = OFF_INPROJB + 256,
  OFF_BLKINB  = OFF_BLKINW + 1048576,
  OFF_CONVW   = OFF_BLKINB + 4096,
  OFF_CONVB   = OFF_CONVW + 8192,
  OFF_XPROJW  = OFF_CONVB + 2048,
  OFF_DTW     = OFF_XPROJW + 98304,
  OFF_DTB     = OFF_DTW + 32768,
  OFF_A       = OFF_DTB + 2048,
  OFF_DP      = OFF_A + 32768,
  OFF_BLKOUTW = OFF_DP + 2048,
  OFF_BLKOUTB = OFF_BLKOUTW + 524288,
  OFF_LNG     = OFF_BLKOUTB + 1024,
  OFF_LNB     = OFF_LNG + 1024,
  OFF_HEADW   = OFF_LNB + 1024,
  OFF_HEADB   = OFF_HEADW + 1536,
  OFF_OUTPW   = OFF_HEADB + 16,
  OFF_OUTPB   = OFF_OUTPW + 1024,
  OFF_X       = OFF_OUTPB + 16,           // f32 (NTOK,256) residual
  OFF_DT      = OFF_X + NTOK*256,         // bf16 (NTOK,512) dt
  OFF_SD      = OFF_DT + NTOK*256,        // f32 (256,512) chunk dt-sums
  OFF_BM      = OFF_SD + 131072,          // f32 (NTOK,16)
  OFF_CM      = OFF_BM + 131072,          // f32 (NTOK,16)
  OFF_XSBL    = OFF_CM + 131072,          // overlay: bf16 xs(NTOK,512), then f32 BLHS(256,512,16)
  OFF_Z16     = OFF_XSBL + NTOK*256,      // bf16 z (NTOK,512)
  OFF_XC16    = OFF_Z16 + NTOK*256,       // bf16 xc (NTOK,512); scan3 overwrites with y
  OFF_X16     = OFF_XC16 + NTOK*256,      // bf16 x (NTOK,256) residual copy (GEMM A)
  OFF_WIN16   = OFF_X16 + NTOK*128,       // bf16 blk_in_w (4,1024,256)
  OFF_WOUT16  = OFF_WIN16 + 524288,       // bf16 blk_out_w (4,256,512)
  OFF_BXD16   = OFF_WOUT16 + 262144,      // bf16 (4,48,512)
  OFF_T16     = OFF_BXD16 + 49152,        // bf16 (NTOK,32) T zero-padded
  OFF_DTW16   = OFF_T16 + NTOK*16,        // bf16 (4,512,32) dtw zero-padded
  OFF_TOT     = OFF_DTW16 + 32768,
};

__device__ inline float bf2f(u16 u) { return __uint_as_float(((u32)u) << 16); }
__device__ inline u16 f2bf(float f) {
  u32 x = __float_as_uint(f);
  u32 r = x + 0x7fffu + ((x >> 16) & 1u);
  return (u16)(r >> 16);
}

// ---- ws_size shortfall sentinel ----
__global__ void k_sentinel(u32* dout, int nw) {
  int i = blockIdx.x * blockDim.x + threadIdx.x;
  if (i < nw) dout[i] = 0x46404640u;
}

// ---- dtype detection ----
__global__ void k_detect(const u16* emb, int n, int* flag) {
  __shared__ int bad;
  if (threadIdx.x == 0) bad = 0;
  __syncthreads();
  int local = 0;
  for (int i = threadIdx.x; i < n; i += blockDim.x) {
    float v = bf2f(emb[i]);
    if (!(fabsf(v) < 100.0f)) local = 1;
  }
  if (local) atomicOr(&bad, 1);
  __syncthreads();
  if (threadIdx.x == 0) flag[0] = bad ? 0 : 1;
}

// ---- convert all float tensors to f32 in ws (op=1: v -> -exp(v)) ----
struct Seg { const void* src; int n; int off; int op; };
struct ConvArgs { Seg seg[21]; int nseg; };

__global__ void k_convert(ConvArgs a, float* ws, const int* flag) {
  int isb = *flag;
  for (int sgi = 0; sgi < a.nseg; sgi++) {
    Seg sg = a.seg[sgi];
    for (int i = blockIdx.x * blockDim.x + threadIdx.x; i < sg.n;
         i += gridDim.x * blockDim.x) {
      float v;
      if (isb) v = bf2f(((const u16*)sg.src)[i]);
      else     v = ((const float*)sg.src)[i];
      if (sg.op) v = -__expf(v);
      ws[sg.off + i] = v;
    }
  }
}

// ---- bf16 copies of GEMM weights (+ dtw16 zero-padded K=32) ----
__global__ void k_w16(float* ws) {
  u16* win = (u16*)(ws + OFF_WIN16);
  u16* wout = (u16*)(ws + OFF_WOUT16);
  u16* dtw16 = (u16*)(ws + OFF_DTW16);
  const int N1 = 1048576, N2 = N1 + 524288, N3 = N2 + 4 * 512 * 32;
  for (int i = blockIdx.x * blockDim.x + threadIdx.x; i < N3;
       i += gridDim.x * blockDim.x) {
    if (i < N1) {
      win[i] = f2bf(ws[OFF_BLKINW + i]);
    } else if (i < N2) {
      wout[i - N1] = f2bf(ws[OFF_BLKOUTW + i - N1]);
    } else {
      int j = i - N2;
      int l = j / (512 * 32), rem = j - l * (512 * 32);
      int row = rem >> 5, k = rem & 31;
      dtw16[j] = (k < 16) ? f2bf(ws[OFF_DTW + l * 8192 + row * 16 + k]) : 0;
    }
  }
}

// ---- build BXD panel: rows 0..31 = xpw[16:48] (B,C); rows 32..47 = xpw[0:16] ----
__global__ void k_bxd(float* ws) {
  u16* bxd = (u16*)(ws + OFF_BXD16);
  const int NXD = 4 * 48 * 512;
  for (int idx = blockIdx.x * blockDim.x + threadIdx.x; idx < NXD;
       idx += gridDim.x * blockDim.x) {
    int l = idx / (48 * 512);
    int rem = idx - l * (48 * 512);
    int row = rem >> 9, k = rem & 511;
    const float* xpw = ws + OFF_XPROJW + l * 24576;
    float v = (row < 32) ? xpw[(16 + row) * 512 + k] : xpw[(row - 32) * 512 + k];
    bxd[idx] = f2bf(v);
  }
}

// ---- x = emb[seq] + input @ inproj_w.T + inproj_b ----
__global__ __launch_bounds__(256) void k_embed(const int* seq, float* ws) {
  int n = blockIdx.x, d = threadIdx.x;
  int s = seq[n];
  float4 iv = *(const float4*)(ws + OFF_INPUT + n * 4);
  float4 wv = *(const float4*)(ws + OFF_INPROJW + d * 4);
  float acc = ws[OFF_EMB + s * 256 + d] + ws[OFF_INPROJB + d]
            + iv.x * wv.x + iv.y * wv.y + iv.z * wv.z + iv.w * wv.w;
  ws[OFF_X + (size_t)n * 256 + d] = acc;
  ((u16*)(ws + OFF_X16))[(size_t)n * 256 + d] = f2bf(acc);
}

// ---- MFMA in-proj: LDS-staged 128x128 tile, K=256 (R13-proven) ----
__global__ __launch_bounds__(256) void k_gemm_in(float* ws, int l) {
  __shared__ u16 As[128][40];
  __shared__ u16 Bs[128][40];
  __shared__ u16 ot[64][136];
  int m0 = blockIdx.x * 128, n0g = blockIdx.y * 128;
  int t = threadIdx.x;
  int w = t >> 6, lane = t & 63;
  int fr = lane & 15, fq = lane >> 4;
  int wr = (w >> 1) * 64, wc = (w & 1) * 64;
  const u16* Ab = (const u16*)(ws + OFF_X16);
  const u16* Bb = (const u16*)(ws + OFF_WIN16) + (size_t)l * 1024 * 256;
  const float* bias = ws + OFF_BLKINB + l * 1024;
  f32x4 acc[4][4] = {};
  for (int k0 = 0; k0 < 256; k0 += 32) {
    __syncthreads();
    #pragma unroll
    for (int cc = 0; cc < 2; cc++) {
      int c = t + cc * 256;
      int row = c >> 2, cg = (c & 3) * 8;
      *(uint4*)&As[row][cg] =
          *(const uint4*)(Ab + (size_t)(m0 + row) * 256 + k0 + cg);
      *(uint4*)&Bs[row][cg] =
          *(const uint4*)(Bb + (size_t)(n0g + row) * 256 + k0 + cg);
    }
    __syncthreads();
    bf16x8 af[4], bf_[4];
    #pragma unroll
    for (int f = 0; f < 4; f++) {
      af[f]  = *(const bf16x8*)&As[wr + f * 16 + fr][fq * 8];
      bf_[f] = *(const bf16x8*)&Bs[wc + f * 16 + fr][fq * 8];
    }
    #pragma unroll
    for (int i = 0; i < 4; i++)
      #pragma unroll
      for (int j = 0; j < 4; j++)
        acc[i][j] = __builtin_amdgcn_mfma_f32_16x16x32_bf16(af[i], bf_[j],
                                                            acc[i][j], 0, 0, 0);
  }
  u16* plane; int cb0;
  if (n0g < 512) { plane = (u16*)(ws + OFF_XSBL); cb0 = n0g; }
  else           { plane = (u16*)(ws + OFF_Z16);  cb0 = n0g - 512; }
  #pragma unroll
  for (int hh = 0; hh < 2; hh++) {
    __syncthreads();
    if ((w >> 1) == hh) {
      #pragma unroll
      for (int i = 0; i < 4; i++)
        #pragma unroll
        for (int j = 0; j < 4; j++) {
          int col = wc + j * 16 + fr;
          float bv = bias[n0g + col];
          #pragma unroll
          for (int r = 0; r < 4; r++)
            ot[i * 16 + fq * 4 + r][col] = f2bf(acc[i][j][r] + bv);
        }
    }
    __syncthreads();
    int row = t >> 2, c0 = (t & 3) * 32;
    uint4 q0 = *(const uint4*)&ot[row][c0];
    uint4 q1 = *(const uint4*)&ot[row][c0 + 8];
    uint4 q2 = *(const uint4*)&ot[row][c0 + 16];
    uint4 q3 = *(const uint4*)&ot[row][c0 + 24];
    u16* dst = plane + (size_t)(m0 + hh * 64 + row) * 512 + cb0 + c0;
    *(uint4*)(dst + 0) = q0;
    *(uint4*)(dst + 8) = q1;
    *(uint4*)(dst + 16) = q2;
    *(uint4*)(dst + 24) = q3;
  }
}

// ---- causal depthwise conv + silu -> xc16 (rolling register window) ----
__global__ __launch_bounds__(512) void k_conv(float* ws, int l) {
  int n0 = blockIdx.x * 16;
  int d = threadIdx.x;
  const float* cw = ws + OFF_CONVW + l * 2048;
  float4 w4 = *(const float4*)(cw + d * 4);
  float cbv = ws[OFF_CONVB + l * 512 + d];
  const u16* xs16 = (const u16*)(ws + OFF_XSBL);
  u16* xc16 = (u16*)(ws + OFF_XC16);
  float xm3, xm2, xm1;
  if ((n0 & (Tlen - 1)) == 0) {
    xm3 = xm2 = xm1 = 0.f;
  } else {
    xm3 = bf2f(xs16[(size_t)(n0 - 3) * 512 + d]);
    xm2 = bf2f(xs16[(size_t)(n0 - 2) * 512 + d]);
    xm1 = bf2f(xs16[(size_t)(n0 - 1) * 512 + d]);
  }
  #pragma unroll
  for (int tok = 0; tok < 16; tok++) {
    int n = n0 + tok;
    float xc = bf2f(xs16[(size_t)n * 512 + d]);
    float acc = cbv + xm3 * w4.x + xm2 * w4.y + xm1 * w4.z + xc * w4.w;
    float sv = acc / (1.f + __expf(-acc));   // silu
    xc16[(size_t)n * 512 + d] = f2bf(sv);
    xm3 = xm2; xm2 = xm1; xm1 = xc;
  }
}

// ---- MFMA B/C/T proj: direct pipelined, 3 B-frags (BM, CM, T->bf16 padded) ----
__global__ __launch_bounds__(256) void k_gemm_bct(float* ws, int l) {
  int m0 = blockIdx.x * 64;
  int w = threadIdx.x >> 6, lane = threadIdx.x & 63;
  const u16* Ab = (const u16*)(ws + OFF_XC16);
  const u16* Bb = (const u16*)(ws + OFF_BXD16) + (size_t)l * 48 * 512;
  int ak = (lane >> 4) * 8;
  const u16* ap = Ab + (size_t)(m0 + w * 16 + (lane & 15)) * 512 + ak;
  int rowbase = w * 16 + (lane >> 4) * 4;
  const u16* bp = Bb + (size_t)(lane & 15) * 512 + ak;
  f32x4 acc[3] = {};
  bf16x8 a0 = *(const bf16x8*)ap;
  bf16x8 b0[3];
  #pragma unroll
  for (int j = 0; j < 3; j++) b0[j] = *(const bf16x8*)(bp + (size_t)j * 8192);
  #pragma unroll 2
  for (int k0 = 1; k0 < 16; k0++) {
    bf16x8 a1 = *(const bf16x8*)(ap + k0 * 32);
    bf16x8 b1[3];
    #pragma unroll
    for (int j = 0; j < 3; j++)
      b1[j] = *(const bf16x8*)(bp + (size_t)j * 8192 + k0 * 32);
    #pragma unroll
    for (int j = 0; j < 3; j++)
      acc[j] = __builtin_amdgcn_mfma_f32_16x16x32_bf16(a0, b0[j], acc[j], 0, 0, 0);
    a0 = a1;
    #pragma unroll
    for (int j = 0; j < 3; j++) b0[j] = b1[j];
  }
  #pragma unroll
  for (int j = 0; j < 3; j++)
    acc[j] = __builtin_amdgcn_mfma_f32_16x16x32_bf16(a0, b0[j], acc[j], 0, 0, 0);
  int c = lane & 15;
  u16* t16 = (u16*)(ws + OFF_T16);
  #pragma unroll
  for (int r = 0; r < 4; r++) {
    ws[OFF_BM + (size_t)(m0 + rowbase + r) * 16 + c] = acc[0][r];
    ws[OFF_CM + (size_t)(m0 + rowbase + r) * 16 + c] = acc[1][r];
    t16[(size_t)(m0 + rowbase + r) * 32 + c] = f2bf(acc[2][r]);
    t16[(size_t)(m0 + rowbase + r) * 32 + 16 + c] = 0;
  }
}

// ---- MFMA dt: dt = softplus(T16 @ dtw16^T + b), K=32 single step ----
// grid (128, 8): 64 rows x 64 cols per block; 4 waves x 4 col-frags
__global__ __launch_bounds__(256) void k_dt16(float* ws, int l) {
  __shared__ u16 dts[64][136];
  int m0 = blockIdx.x * 64;
  int c0g = blockIdx.y * 64;
  int t = threadIdx.x;
  int w = t >> 6, lane = t & 63;
  int fr = lane & 15, fq = lane >> 4;
  const u16* Ab = (const u16*)(ws + OFF_T16);
  const u16* Bb = (const u16*)(ws + OFF_DTW16) + (size_t)l * 512 * 32;
  bf16x8 a = *(const bf16x8*)(Ab + (size_t)(m0 + w * 16 + fr) * 32 + fq * 8);
  f32x4 acc[4] = {};
  #pragma unroll
  for (int j = 0; j < 4; j++) {
    bf16x8 b = *(const bf16x8*)(Bb + (size_t)(c0g + j * 16 + fr) * 32 + fq * 8);
    acc[j] = __builtin_amdgcn_mfma_f32_16x16x32_bf16(a, b, acc[j], 0, 0, 0);
  }
  const float* dtb = ws + OFF_DTB + l * 512;
  int rowbase = w * 16 + fq * 4;
  #pragma unroll
  for (int j = 0; j < 4; j++) {
    float bv = dtb[c0g + j * 16 + fr];
    #pragma unroll
    for (int r = 0; r < 4; r++) {
      float s = acc[j][r] + bv;
      float dtv = (s > 20.f) ? s : log1pf(__expf(s));
      dts[rowbase + r][j * 16 + fr] = f2bf(dtv);
    }
  }
  __syncthreads();
  u16* dt16 = (u16*)(ws + OFF_DT);
  int row = t >> 2, part = t & 3;
  uint4 v0 = *(const uint4*)&dts[row][part * 16];
  uint4 v1 = *(const uint4*)&dts[row][part * 16 + 8];
  u16* dst = dt16 + (size_t)(m0 + row) * 512 + c0g + part * 16;
  *(uint4*)dst = v0;
  *(uint4*)(dst + 8) = v1;
}

// ---- scan phase 1: double-buffered LDS staging; local scan -> SD, BL ----
__global__ __launch_bounds__(512) void k_scan1(float* ws, int l) {
  __shared__ u16 dt_s[8][512];
  __shared__ u16 xc_s[8][512];
  __shared__ float Bls[CH * 16];
  int blk = blockIdx.x;
  int b = blk >> 7, ch = blk & 127;
  int d = threadIdx.x;
  int nbase = b * Tlen + ch * CH;
  Bls[d] = ws[OFF_BM + (size_t)nbase * 16 + d];
  const float* Ap = ws + OFF_A + l * 8192 + d * 16;
  float Ar[16];
  *(float4*)&Ar[0]  = *(const float4*)(Ap + 0);
  *(float4*)&Ar[4]  = *(const float4*)(Ap + 4);
  *(float4*)&Ar[8]  = *(const float4*)(Ap + 8);
  *(float4*)&Ar[12] = *(const float4*)(Ap + 12);
  float h[16];
  #pragma unroll
  for (int s = 0; s < 16; s++) h[s] = 0.f;
  float sumdt = 0.f;
  const u16* dtg = (const u16*)(ws + OFF_DT) + (size_t)nbase * 512;
  const u16* xcg = (const u16*)(ws + OFF_XC16) + (size_t)nbase * 512;
  int lr = d >> 6, lc = (d & 63) * 8;
  uint4 pd = *(const uint4*)(dtg + (size_t)lr * 512 + lc);
  uint4 px = *(const uint4*)(xcg + (size_t)lr * 512 + lc);
  for (int st = 0; st < 4; st++) {
    *(uint4*)&dt_s[lr][lc] = pd;
    *(uint4*)&xc_s[lr][lc] = px;
    if (st < 3) {
      pd = *(const uint4*)(dtg + (size_t)(st * 8 + 8 + lr) * 512 + lc);
      px = *(const uint4*)(xcg + (size_t)(st * 8 + 8 + lr) * 512 + lc);
    }
    __syncthreads();
    #pragma unroll
    for (int tk = 0; tk < 8; tk++) {
      int tt = st * 8 + tk;
      float dtv = bf2f(dt_s[tk][d]);
      float xv = bf2f(xc_s[tk][d]);
      sumdt += dtv;
      float dtx = dtv * xv;
      #pragma unroll
      for (int s = 0; s < 16; s++)
        h[s] = __expf(dtv * Ar[s]) * h[s] + dtx * Bls[tt * 16 + s];
    }
    __syncthreads();
  }
  ws[OFF_SD + (size_t)blk * 512 + d] = sumdt;
  float* bl = ws + OFF_XSBL + ((size_t)blk * 512 + d) * 16;
  *(float4*)(bl + 0)  = make_float4(h[0], h[1], h[2], h[3]);
  *(float4*)(bl + 4)  = make_float4(h[4], h[5], h[6], h[7]);
  *(float4*)(bl + 8)  = make_float4(h[8], h[9], h[10], h[11]);
  *(float4*)(bl + 12) = make_float4(h[12], h[13], h[14], h[15]);
}

// ---- scan phase 2: sequential chunk prefix, depth-4 prefetch pipeline ----
__global__ __launch_bounds__(256) void k_scan2(float* ws, int l) {
  int q = blockIdx.x * 256 + threadIdx.x;   // 2*512*16 total
  int b = q >> 13, ds = q & 8191, d = ds >> 4;
  float Av = ws[OFF_A + l * 8192 + ds];
  float* blhs = ws + OFF_XSBL;
  const float* sdp = ws + OFF_SD;
  size_t base = (size_t)(b * NCH) * 8192 + ds;
  size_t sbase = (size_t)(b * NCH) * 512 + d;
  float blv[4], sd[4];
  #pragma unroll
  for (int k = 0; k < 4; k++) {
    blv[k] = blhs[base + (size_t)k * 8192];
    sd[k] = sdp[sbase + (size_t)k * 512];
  }
  float h = 0.f;
  for (int g = 0; g < 32; g++) {
    float nblv[4], nsd[4];
    if (g < 31) {
      #pragma unroll
      for (int k = 0; k < 4; k++) {
        nblv[k] = blhs[base + (size_t)(g * 4 + 4 + k) * 8192];
        nsd[k] = sdp[sbase + (size_t)(g * 4 + 4 + k) * 512];
      }
    }
    #pragma unroll
    for (int k = 0; k < 4; k++) {
      blhs[base + (size_t)(g * 4 + k) * 8192] = h;   // h at chunk start
      h = __expf(sd[k] * Av) * h + blv[k];
    }
    #pragma unroll
    for (int k = 0; k < 4; k++) { blv[k] = nblv[k]; sd[k] = nsd[k]; }
  }
}

// ---- scan phase 3: double-buffered staging; y -> bf16 over xc plane ----
__global__ __launch_bounds__(512) void k_scan3(float* ws, int l) {
  __shared__ u16 dt_s[8][512];
  __shared__ u16 xc_s[8][512];
  __shared__ u16 z_s[8][512];
  __shared__ u16 y_s[8][512];
  __shared__ float Bls[CH * 16];
  __shared__ float Cls[CH * 16];
  int blk = blockIdx.x;
  int b = blk >> 7, ch = blk & 127;
  int d = threadIdx.x;
  int nbase = b * Tlen + ch * CH;
  Bls[d] = ws[OFF_BM + (size_t)nbase * 16 + d];
  Cls[d] = ws[OFF_CM + (size_t)nbase * 16 + d];
  const float* Ap = ws + OFF_A + l * 8192 + d * 16;
  float Ar[16];
  *(float4*)&Ar[0]  = *(const float4*)(Ap + 0);
  *(float4*)&Ar[4]  = *(const float4*)(Ap + 4);
  *(float4*)&Ar[8]  = *(const float4*)(Ap + 8);
  *(float4*)&Ar[12] = *(const float4*)(Ap + 12);
  float Dv = ws[OFF_DP + l * 512 + d];
  const float* hs = ws + OFF_XSBL + ((size_t)blk * 512 + d) * 16;
  float h[16];
  *(float4*)&h[0]  = *(const float4*)(hs + 0);
  *(float4*)&h[4]  = *(const float4*)(hs + 4);
  *(float4*)&h[8]  = *(const float4*)(hs + 8);
  *(float4*)&h[12] = *(const float4*)(hs + 12);
  const u16* dtg = (const u16*)(ws + OFF_DT) + (size_t)nbase * 512;
  u16* xcg = (u16*)(ws + OFF_XC16) + (size_t)nbase * 512;  // xc in, y out
  const u16* zg = (const u16*)(ws + OFF_Z16) + (size_t)nbase * 512;
  int lr = d >> 6, lc = (d & 63) * 8;
  size_t off0 = (size_t)lr * 512 + lc;
  uint4 pd = *(const uint4*)(dtg + off0);
  uint4 px = *(const uint4*)(xcg + off0);
  uint4 pz = *(const uint4*)(zg + off0);
  for (int st = 0; st < 4; st++) {
    size_t goff = (size_t)(st * 8 + lr) * 512 + lc;
    *(uint4*)&dt_s[lr][lc] = pd;
    *(uint4*)&xc_s[lr][lc] = px;
    *(uint4*)&z_s[lr][lc]  = pz;
    if (st < 3) {
      size_t noff = (size_t)(st * 8 + 8 + lr) * 512 + lc;
      pd = *(const uint4*)(dtg + noff);
      px = *(const uint4*)(xcg + noff);
      pz = *(const uint4*)(zg + noff);
    }
    __syncthreads();
    #pragma unroll
    for (int tk = 0; tk < 8; tk++) {
      int tt = st * 8 + tk;
      float dtv = bf2f(dt_s[tk][d]);
      float xv = bf2f(xc_s[tk][d]);
      float dtx = dtv * xv;
      float yacc = 0.f;
      #pragma unroll
      for (int s = 0; s < 16; s++) {
        h[s] = __expf(dtv * Ar[s]) * h[s] + dtx * Bls[tt * 16 + s];
        yacc += h[s] * Cls[tt * 16 + s];
      }
      float yv = yacc + Dv * xv;
      float zv = bf2f(z_s[tk][d]);
      float sz = zv / (1.f + __expf(-zv));
      y_s[tk][d] = f2bf(yv * sz);
    }
    __syncthreads();
    *(uint4*)(xcg + goff) = *(const uint4*)&y_s[lr][lc];
  }
}

// ---- MFMA out-proj: pipelined k-loop + residual + layernorm fused ----
__global__ __launch_bounds__(256) void k_gemm_out(float* ws, int l) {
  __shared__ float mxs[16][260];
  int m0 = blockIdx.x * 16;
  int w = threadIdx.x >> 6, lane = threadIdx.x & 63;
  const u16* Ab = (const u16*)(ws + OFF_XC16);   // y bf16
  const u16* Bb = (const u16*)(ws + OFF_WOUT16) + (size_t)l * 256 * 512;
  int ak = (lane >> 4) * 8;
  const u16* ap = Ab + (size_t)(m0 + (lane & 15)) * 512 + ak;
  const u16* bp = Bb + (size_t)(w * 64 + (lane & 15)) * 512 + ak;
  f32x4 acc[4] = {};
  bf16x8 a0 = *(const bf16x8*)ap;
  bf16x8 b0[4];
  #pragma unroll
  for (int j = 0; j < 4; j++) b0[j] = *(const bf16x8*)(bp + (size_t)j * 8192);
  #pragma unroll 2
  for (int k0 = 1; k0 < 16; k0++) {
    bf16x8 a1 = *(const bf16x8*)(ap + k0 * 32);
    bf16x8 b1[4];
    #pragma unroll
    for (int j = 0; j < 4; j++)
      b1[j] = *(const bf16x8*)(bp + (size_t)j * 8192 + k0 * 32);
    #pragma unroll
    for (int j = 0; j < 4; j++)
      acc[j] = __builtin_amdgcn_mfma_f32_16x16x32_bf16(a0, b0[j], acc[j], 0, 0, 0);
    a0 = a1;
    #pragma unroll
    for (int j = 0; j < 4; j++) b0[j] = b1[j];
  }
  #pragma unroll
  for (int j = 0; j < 4; j++)
    acc[j] = __builtin_amdgcn_mfma_f32_16x16x32_bf16(a0, b0[j], acc[j], 0, 0, 0);
  const float* ob = ws + OFF_BLKOUTB + l * 256;
  int rl = (lane >> 4) * 4;
  #pragma unroll
  for (int j = 0; j < 4; j++) {
    int c = w * 64 + j * 16 + (lane & 15);
    float bv = ob[c];
    #pragma unroll
    for (int r = 0; r < 4; r++)
      mxs[rl + r][c] = acc[j][r] + bv;
  }
  __syncthreads();
  int t = threadIdx.x;
  int g = t >> 4, ln = t & 15;
  int n = m0 + g;
  float* x = ws + OFF_X;
  const float* gamma = ws + OFF_LNG + l * 256;
  const float* beta = ws + OFF_LNB + l * 256;
  float v[16], s1 = 0.f, s2 = 0.f;
  #pragma unroll
  for (int i = 0; i < 16; i++) {
    int c = ln + i * 16;
    float xv = x[(size_t)n * 256 + c] + mxs[g][c];
    v[i] = xv; s1 += xv; s2 += xv * xv;
  }
  #pragma unroll
  for (int m = 8; m >= 1; m >>= 1) {
    s1 += __shfl_xor(s1, m, 64);
    s2 += __shfl_xor(s2, m, 64);
  }
  float mu = s1 * (1.f / 256.f);
  float var = s2 * (1.f / 256.f) - mu * mu;
  float rs = rsqrtf(var + 1e-5f);
  #pragma unroll
  for (int i = 0; i < 16; i++) {
    int c = ln + i * 16;
    mxs[g][c] = (v[i] - mu) * rs * gamma[c] + beta[c];
  }
  __syncthreads();
  int row = t >> 4, cb = (t & 15) * 16;
  float4 f0 = *(const float4*)&mxs[row][cb + 0];
  float4 f1 = *(const float4*)&mxs[row][cb + 4];
  float4 f2 = *(const float4*)&mxs[row][cb + 8];
  float4 f3 = *(const float4*)&mxs[row][cb + 12];
  float* xd = x + (size_t)(m0 + row) * 256 + cb;
  *(float4*)(xd + 0) = f0;
  *(float4*)(xd + 4) = f1;
  *(float4*)(xd + 8) = f2;
  *(float4*)(xd + 12) = f3;
  u32 p[8];
  p[0] = (u32)f2bf(f0.x) | ((u32)f2bf(f0.y) << 16);
  p[1] = (u32)f2bf(f0.z) | ((u32)f2bf(f0.w) << 16);
  p[2] = (u32)f2bf(f1.x) | ((u32)f2bf(f1.y) << 16);
  p[3] = (u32)f2bf(f1.z) | ((u32)f2bf(f1.w) << 16);
  p[4] = (u32)f2bf(f2.x) | ((u32)f2bf(f2.y) << 16);
  p[5] = (u32)f2bf(f2.z) | ((u32)f2bf(f2.w) << 16);
  p[6] = (u32)f2bf(f3.x) | ((u32)f2bf(f3.y) << 16);
  p[7] = (u32)f2bf(f3.z) | ((u32)f2bf(f3.w) << 16);
  u16* xd16 = (u16*)(ws + OFF_X16) + (size_t)(m0 + row) * 256 + cb;
  *(uint4*)(xd16 + 0) = *(uint4*)&p[0];
  *(uint4*)(xd16 + 8) = *(uint4*)&p[4];
}

// ---- heads ----
__global__ __launch_bounds__(256) void k_head(const float* ws, void* dout,
                                              const int* flag) {
  int t = threadIdx.x;
  int lane = t & 63, w = t >> 6;
  int n = blockIdx.x * 4 + w;
  const float* xr = ws + OFF_X + (size_t)n * 256;
  float xv[4];
  #pragma unroll
  for (int i = 0; i < 4; i++) xv[i] = xr[lane + 64 * i];
  float res[10];
  #pragma unroll
  for (int o = 0; o < 10; o++) {
    const float* wr = (o < 6) ? ws + OFF_HEADW + o * 256
                              : ws + OFF_OUTPW + (o - 6) * 256;
    float p = 0.f;
    #pragma unroll
    for (int i = 0; i < 4; i++) p += xv[i] * wr[lane + 64 * i];
    #pragma unroll
    for (int m = 32; m >= 1; m >>= 1) p += __shfl_xor(p, m, 64);
    res[o] = p;
  }
  int isb = flag[0];
  if (lane < 6) {
    float vv = res[lane] + ws[OFF_HEADB + lane];
    size_t idx = (size_t)n * 6 + lane;
    if (isb) ((u16*)dout)[idx] = f2bf(vv);
    else     ((float*)dout)[idx] = vv;
  } else if (lane < 10) {
    int o = lane - 6;
    float vv = res[lane] + ws[OFF_OUTPB + o];
    size_t idx = (size_t)NTOK * 6 + (size_t)n * 4 + o;
    if (isb) ((u16*)dout)[idx] = f2bf(vv);
    else     ((float*)dout)[idx] = vv;
  }
}

extern "C" void kernel_launch(void* const* d_in, const int* in_sizes, int n_in,
                              void* d_out, int out_size, void* d_ws, size_t ws_size,
                              hipStream_t stream) {
  (void)n_in;
  float* ws = (float*)d_ws;
  int* flag = (int*)d_ws;

  if (ws_size < (size_t)OFF_TOT * 4) {
    int nw = out_size / 2;
    k_sentinel<<<(nw + 255) / 256, 256, 0, stream>>>((u32*)d_out, nw);
    return;
  }

  k_detect<<<1, 256, 0, stream>>>((const u16*)d_in[2], in_sizes[2], flag);

  ConvArgs ca;
  int i = 0;
  auto add = [&](int idx, int n, int off, int op) {
    ca.seg[i].src = d_in[idx]; ca.seg[i].n = n;
    ca.seg[i].off = off; ca.seg[i].op = op; i++;
  };
  add(2, 1536, OFF_EMB, 0);      add(1, 32768, OFF_INPUT, 0);
  add(3, 1024, OFF_INPROJW, 0);  add(4, 256, OFF_INPROJB, 0);
  add(5, 1048576, OFF_BLKINW, 0); add(6, 4096, OFF_BLKINB, 0);
  add(7, 8192, OFF_CONVW, 0);    add(8, 2048, OFF_CONVB, 0);
  add(9, 98304, OFF_XPROJW, 0);  add(10, 32768, OFF_DTW, 0);
  add(11, 2048, OFF_DTB, 0);     add(12, 32768, OFF_A, 1);  // A = -exp(A_log)
  add(13, 2048, OFF_DP, 0);      add(14, 524288, OFF_BLKOUTW, 0);
  add(15, 1024, OFF_BLKOUTB, 0); add(16, 1024, OFF_LNG, 0);
  add(17, 1024, OFF_LNB, 0);     add(18, 1536, OFF_HEADW, 0);
  add(19, 6, OFF_HEADB, 0);      add(20, 1024, OFF_OUTPW, 0);
  add(21, 4, OFF_OUTPB, 0);
  ca.nseg = i;
  k_convert<<<512, 256, 0, stream>>>(ca, ws, flag);
  k_w16<<<512, 256, 0, stream>>>(ws);
  k_bxd<<<384, 256, 0, stream>>>(ws);

  k_embed<<<NTOK, 256, 0, stream>>>((const int*)d_in[0], ws);

  for (int l = 0; l < 4; l++) {
    k_gemm_in<<<dim3(64, 8), 256, 0, stream>>>(ws, l);
    k_conv<<<NTOK / 16, 512, 0, stream>>>(ws, l);
    k_gemm_bct<<<128, 256, 0, stream>>>(ws, l);
    k_dt16<<<dim3(128, 8), 256, 0, stream>>>(ws, l);
    k_scan1<<<2 * NCH, 512, 0, stream>>>(ws, l);
    k_scan2<<<64, 256, 0, stream>>>(ws, l);
    k_scan3<<<2 * NCH, 512, 0, stream>>>(ws, l);
    k_gemm_out<<<NTOK / 16, 256, 0, stream>>>(ws, l);
  }

  k_head<<<NTOK / 4, 256, 0, stream>>>(ws, d_out, flag);
}